// Round 1
// baseline (1699.203 us; speedup 1.0000x reference)
//
#include <hip/hip_runtime.h>
#include <math.h>

// Problem constants (from reference setup_inputs)
#define NS    16
#define MAXL  513          // largest wavelet length (512 -> odd -> 513), pad<=256
#define T_LEN 8192
#define BATCH 8
#define CH    32

// Tiling
#define TW    256          // T positions produced per block
#define BT    256          // threads per block
#define CWID  (TW + 4)     // cwt tile width (halo 2 each side)
#define H1W   (TW + 2)     // h1 tile width (halo 1 each side)
#define XWIN  (TW + 516)   // x window: TW + 2*2 (dw halo) + 2*256 (max pad)

__device__ __forceinline__ float gelu_exact(float v) {
    return 0.5f * v * (1.0f + erff(v * 0.70710678118654752440f));
}

// Recompute wavelet tables every launch (d_ws is re-poisoned before timed calls).
// Double precision exactly mirrors numpy: logspace exponents, int() truncation,
// linspace step = (hi-lo)/(L-1) with forced endpoint.
__global__ void wavelet_init(float* __restrict__ wav /*[NS][MAXL][2] interleaved*/,
                             int* __restrict__ Ls) {
    int idx0   = blockIdx.x * blockDim.x + threadIdx.x;
    int stride = gridDim.x * blockDim.x;
    for (int idx = idx0; idx < NS * MAXL; idx += stride) {
        int s = idx / MAXL;
        int j = idx - s * MAXL;
        double e = (s == NS - 1) ? log10(200.0)
                                 : (log10(2.0) + (double)s * ((log10(200.0) - log10(2.0)) / 15.0));
        double sc = pow(10.0, e);
        int L = (int)(6.0 * sc);
        if (L > 512) L = 512;
        if ((L & 1) == 0) L += 1;
        if (j == 0) Ls[s] = L;
        float r = 0.f, im = 0.f;
        if (j < L) {
            double lo   = -(double)((L + 1) / 2);   // Python (-L)//2 for odd L
            double hi   =  (double)(L / 2);
            double step = (hi - lo) / (double)(L - 1);
            double t    = (j == L - 1) ? hi : (lo + (double)j * step);
            double ts   = t / sc;
            double norm = 1.0 / (pow(M_PI, 0.25) * sqrt(sc));
            double g    = norm * exp(-(ts * ts) * 0.5);
            r  = (float)(g * cos(5.0 * ts));
            im = (float)(g * sin(5.0 * ts));
        }
        wav[idx * 2 + 0] = r;
        wav[idx * 2 + 1] = im;
    }
}

__global__ __launch_bounds__(BT) void wlsc_main(
    const float* __restrict__ x,
    const float* __restrict__ w1, const float* __restrict__ b1,
    const float* __restrict__ w2, const float* __restrict__ b2,
    const float* __restrict__ blend_logit,
    const float* __restrict__ lsc,
    const float* __restrict__ wav,      // [NS][MAXL][2] interleaved (r,i)
    const int*   __restrict__ Ls,
    float* __restrict__ out)
{
    __shared__ float xw[XWIN];
    __shared__ float cwt[NS * CWID];
    __shared__ float h1[NS * H1W];
    __shared__ float corr[NS];
    __shared__ int   sL[NS];

    const int tile = blockIdx.x;          // 0 .. T_LEN/TW-1
    const int bc   = blockIdx.y;          // 0 .. BATCH*CH-1
    const int t0   = tile * TW;
    const int tid  = threadIdx.x;
    const int c    = bc & (CH - 1);
    const float* xbc = x + (size_t)bc * T_LEN;

    if (tid < NS) {
        corr[tid] = expf(lsc[tid]);       // exp(log_scale_corrections)
        sL[tid]   = Ls[tid];
    }

    // ---- stage x window with reflect padding (single reflection: pad<=256<T) ----
    for (int i = tid; i < XWIN; i += BT) {
        int gi = t0 - 258 + i;
        if (gi < 0)       gi = -gi;
        if (gi >= T_LEN)  gi = 2 * T_LEN - 2 - gi;
        xw[i] = xbc[gi];
    }
    __syncthreads();

    // ---- CWT magnitudes for all scales over [t0-2, t0+TW+2) ----
    // cwt[s*CWID + tt] <-> t_abs = t0 - 2 + tt ; out-of-range t_abs -> 0
    // (feeds SAME zero-padding of the depthwise conv at global edges)
    for (int item = tid; item < NS * CWID; item += BT) {
        int s  = item / CWID;
        int tt = item - s * CWID;
        int t_abs = t0 - 2 + tt;
        float mag = 0.f;
        if (t_abs >= 0 && t_abs < T_LEN) {
            int L   = sL[s];
            int pad = L >> 1;
            const float2* wv = (const float2*)(wav + s * (MAXL * 2)); // 8B aligned
            const float*  xp = xw + (tt + 256 - pad);
            float ar = 0.f, ai = 0.f;
            for (int j = 0; j < L; ++j) {
                float2 w  = wv[j];          // wave-uniform address -> L1 broadcast
                float  xv = xp[j];          // consecutive lanes -> conflict-free LDS
                ar = fmaf(xv, w.x, ar);
                ai = fmaf(xv, w.y, ai);
            }
            mag = sqrtf(ar * ar + ai * ai);
        }
        cwt[item] = mag;
    }
    __syncthreads();

    // per-channel conv weights -> registers (compile-time indexed after unroll)
    float W1[9], W2[9];
    #pragma unroll
    for (int k = 0; k < 9; ++k) { W1[k] = w1[c * 9 + k]; W2[k] = w2[c * 9 + k]; }
    const float B1 = b1[c], B2 = b2[c];
    const float blend = 1.f / (1.f + expf(-blend_logit[0]));

    // ---- h1 = GELU(dwconv1(cwt * scale_corr)) over [t0-1, t0+TW+1) ----
    for (int item = tid; item < NS * H1W; item += BT) {
        int s   = item / H1W;
        int tt1 = item - s * H1W;
        int t_abs = t0 - 1 + tt1;
        float v = 0.f;                      // SAME zero-pad outside [0,T)
        if (t_abs >= 0 && t_abs < T_LEN) {
            float acc = B1;
            #pragma unroll
            for (int ds = 0; ds < 3; ++ds) {
                int s2 = s + ds - 1;
                if ((unsigned)s2 < (unsigned)NS) {
                    float cr = corr[s2];
                    const float* row = cwt + s2 * CWID + tt1;  // cwt tt = tt1+dt
                    acc = fmaf(row[0] * cr, W1[ds * 3 + 0], acc);
                    acc = fmaf(row[1] * cr, W1[ds * 3 + 1], acc);
                    acc = fmaf(row[2] * cr, W1[ds * 3 + 2], acc);
                }
            }
            v = gelu_exact(acc);
        }
        h1[item] = v;
    }
    __syncthreads();

    // ---- h2 = GELU(dwconv2(h1)); blend; ratio mean over scales; out = x * mean ----
    for (int tt2 = tid; tt2 < TW; tt2 += BT) {
        float racc = 0.f;
        #pragma unroll
        for (int s = 0; s < NS; ++s) {
            float acc = B2;
            #pragma unroll
            for (int ds = 0; ds < 3; ++ds) {
                int s2 = s + ds - 1;                 // compile-time bound check
                if ((unsigned)s2 < (unsigned)NS) {
                    const float* row = h1 + s2 * H1W + tt2;    // h1 tt1 = tt2+dt
                    acc = fmaf(row[0], W2[ds * 3 + 0], acc);
                    acc = fmaf(row[1], W2[ds * 3 + 1], acc);
                    acc = fmaf(row[2], W2[ds * 3 + 2], acc);
                }
            }
            float h2v = gelu_exact(acc);
            float cv  = cwt[s * CWID + tt2 + 2];
            float bl  = blend * h2v + (1.f - blend) * cv;
            racc += bl / (cv + 1e-8f);
        }
        out[(size_t)bc * T_LEN + t0 + tt2] = xw[258 + tt2] * racc * (1.f / 16.f);
    }
}

extern "C" void kernel_launch(void* const* d_in, const int* in_sizes, int n_in,
                              void* d_out, int out_size, void* d_ws, size_t ws_size,
                              hipStream_t stream) {
    const float* x  = (const float*)d_in[0];
    const float* w1 = (const float*)d_in[1];
    const float* b1 = (const float*)d_in[2];
    const float* w2 = (const float*)d_in[3];
    const float* b2 = (const float*)d_in[4];
    const float* bl = (const float*)d_in[5];
    const float* ls = (const float*)d_in[6];
    float* out = (float*)d_out;

    // workspace layout: interleaved wavelets [NS][MAXL][2] f32, then L[NS] i32
    float* wav = (float*)d_ws;
    int*   L   = (int*)((char*)d_ws + (size_t)NS * MAXL * 2 * sizeof(float));

    hipLaunchKernelGGL(wavelet_init, dim3(32), dim3(256), 0, stream, wav, L);

    dim3 grid(T_LEN / TW, BATCH * CH);
    hipLaunchKernelGGL(wlsc_main, grid, dim3(BT), 0, stream,
                       x, w1, b1, w2, b2, bl, ls, wav, L, out);
}

// Round 2
// 637.453 us; speedup vs baseline: 2.6656x; 2.6656x over previous
//
#include <hip/hip_runtime.h>
#include <math.h>

// Problem constants
#define NS     16
#define T_LEN  8192
#define BATCH  8
#define CH     32

// Tiling: TW outputs/block; cwt tile = TW+4 = 256 = 64 lanes * 4 outputs
#define TW     252
#define BT     256
#define NTILES 33          // ceil(8192/252)
#define CWW    256         // cwt tile width (TW+4)
#define RS     256         // row stride for cwt/h1 tiles in LDS
#define XWIN   776         // x window: covers [t0-262, t0+514)
#define XBASE  262

// Per-scale constants (match wavelet_init's math; validated round 1)
constexpr int LT[NS]    = {13,17,23,31,41,55,75,103,139,191,259,351,477,513,513,513};
constexpr int PADT[NS]  = {6,8,11,15,20,27,37,51,69,95,129,175,238,256,256,256};
// j0 = (3 - pad) & 3  -> leading zero-taps so the sliding-window x load is 16B aligned
constexpr int J0T[NS]   = {1,3,0,0,3,0,2,0,2,0,2,0,1,3,3,3};
// Lpad = align4(j0 + L)  (trailing zero-taps)
constexpr int LPADT[NS] = {16,20,24,32,44,56,80,104,144,192,264,352,480,516,516,516};
// packed float offsets (2*Lpad prefix) — all multiples of 8 -> 16B-aligned rows
constexpr int WOFFT[NS] = {0,32,72,120,184,272,384,544,752,1040,1424,1952,2656,3616,4648,5680};
#define TOTW      6712     // total packed floats
#define TOTSLOTS  3356     // packed float2 slots

// LPT balance of scales over 4 waves: tap sums 826/833/827/828
constexpr int USCALE[NS] = {13,10,4,0, 14,9,6,3,2, 15,8,7,5,1, 12,11};
constexpr int UOFF[5]    = {0,4,9,14,16};

__device__ __forceinline__ float gelu_exact(float v) {
    return 0.5f * v * (1.0f + erff(v * 0.70710678118654752440f));
}

// Regenerate packed wavelet table every launch (d_ws re-poisoned each call).
// Packed layout: per scale s, LPADT[s] float2 slots at WOFFT[s]; slot k holds
// tap j = k - J0T[s] (zeros outside [0,L)). Double precision mirrors numpy.
__global__ void wavelet_init(float* __restrict__ wavg) {
    int idx0   = blockIdx.x * blockDim.x + threadIdx.x;
    int stride = gridDim.x * blockDim.x;
    for (int idx = idx0; idx < TOTSLOTS; idx += stride) {
        int s = 0;
        while (s < NS - 1 && idx >= (WOFFT[s + 1] >> 1)) ++s;
        int k = idx - (WOFFT[s] >> 1);
        int L = LT[s];
        int j = k - J0T[s];
        float r = 0.f, im = 0.f;
        if (j >= 0 && j < L) {
            double e  = (s == NS - 1) ? log10(200.0)
                                      : (log10(2.0) + (double)s * ((log10(200.0) - log10(2.0)) / 15.0));
            double sc = pow(10.0, e);
            double lo = -(double)((L + 1) / 2);     // Python (-L)//2, L odd
            double hi =  (double)(L / 2);
            double st = (hi - lo) / (double)(L - 1);
            double t  = (j == L - 1) ? hi : (lo + (double)j * st);
            double ts = t / sc;
            double nm = 1.0 / (pow(M_PI, 0.25) * sqrt(sc));
            double g  = nm * exp(-(ts * ts) * 0.5);
            r  = (float)(g * cos(5.0 * ts));
            im = (float)(g * sin(5.0 * ts));
        }
        wavg[2 * idx]     = r;
        wavg[2 * idx + 1] = im;
    }
}

__global__ __launch_bounds__(BT, 3) void wlsc_main(
    const float* __restrict__ x,
    const float* __restrict__ w1, const float* __restrict__ b1,
    const float* __restrict__ w2, const float* __restrict__ b2,
    const float* __restrict__ blend_logit,
    const float* __restrict__ lsc,
    const float* __restrict__ wavg,
    float* __restrict__ out)
{
    __shared__ float xw[XWIN];
    __shared__ float cwtb[NS * RS];
    __shared__ float reg2[TOTW];          // wavelets during stage1; h1 afterwards
    __shared__ float corr[NS];

    const int tid  = threadIdx.x;
    const int tile = blockIdx.x;
    const int bc   = blockIdx.y;
    const int t0   = tile * TW;
    const int c    = bc & (CH - 1);
    const float* xbc = x + (size_t)bc * T_LEN;

    if (tid < NS) corr[tid] = expf(lsc[tid]);

    // stage wavelets (packed) and x window (reflect pad) into LDS
    for (int i = tid; i < TOTW; i += BT) reg2[i] = wavg[i];
    for (int i = tid; i < XWIN; i += BT) {
        int gi = t0 - XBASE + i;
        if (gi < 0)      gi = -gi;
        if (gi >= T_LEN) gi = 2 * T_LEN - 2 - gi;
        xw[i] = xbc[gi];
    }
    __syncthreads();

    // ---- stage 1: CWT magnitudes. One wave = one scale at a time;
    // lane computes 4 consecutive outputs tt0..tt0+3 via sliding window. ----
    const int wid  = tid >> 6;
    const int lane = tid & 63;
    const int tt0  = lane << 2;
    for (int u = UOFF[wid]; u < UOFF[wid + 1]; ++u) {
        const int s   = __builtin_amdgcn_readfirstlane(USCALE[u]);
        const int pad = PADT[s];
        const int j0  = J0T[s];
        const int nb  = LPADT[s] >> 2;
        const float* wp = reg2 + WOFFT[s];
        const float* xp = xw + (tt0 + 260 - pad - j0);   // x for (tap k, out m) = xp[k+m]
        float ar0=0.f,ar1=0.f,ar2=0.f,ar3=0.f, ai0=0.f,ai1=0.f,ai2=0.f,ai3=0.f;
        float h0 = xp[0], h1v = xp[1], h2 = xp[2];
        #pragma unroll 2
        for (int b = 0; b < nb; ++b) {
            const int k = b << 2;
            float4 n  = *reinterpret_cast<const float4*>(xp + k + 3);  // 16B aligned by j0
            float4 wA = *reinterpret_cast<const float4*>(wp + 2 * k);      // taps k,k+1 (r,i,r,i)
            float4 wB = *reinterpret_cast<const float4*>(wp + 2 * k + 4);  // taps k+2,k+3
            // tap k
            ar0=fmaf(h0 ,wA.x,ar0); ai0=fmaf(h0 ,wA.y,ai0);
            ar1=fmaf(h1v,wA.x,ar1); ai1=fmaf(h1v,wA.y,ai1);
            ar2=fmaf(h2 ,wA.x,ar2); ai2=fmaf(h2 ,wA.y,ai2);
            ar3=fmaf(n.x,wA.x,ar3); ai3=fmaf(n.x,wA.y,ai3);
            // tap k+1
            ar0=fmaf(h1v,wA.z,ar0); ai0=fmaf(h1v,wA.w,ai0);
            ar1=fmaf(h2 ,wA.z,ar1); ai1=fmaf(h2 ,wA.w,ai1);
            ar2=fmaf(n.x,wA.z,ar2); ai2=fmaf(n.x,wA.w,ai2);
            ar3=fmaf(n.y,wA.z,ar3); ai3=fmaf(n.y,wA.w,ai3);
            // tap k+2
            ar0=fmaf(h2 ,wB.x,ar0); ai0=fmaf(h2 ,wB.y,ai0);
            ar1=fmaf(n.x,wB.x,ar1); ai1=fmaf(n.x,wB.y,ai1);
            ar2=fmaf(n.y,wB.x,ar2); ai2=fmaf(n.y,wB.y,ai2);
            ar3=fmaf(n.z,wB.x,ar3); ai3=fmaf(n.z,wB.y,ai3);
            // tap k+3
            ar0=fmaf(n.x,wB.z,ar0); ai0=fmaf(n.x,wB.w,ai0);
            ar1=fmaf(n.y,wB.z,ar1); ai1=fmaf(n.y,wB.w,ai1);
            ar2=fmaf(n.z,wB.z,ar2); ai2=fmaf(n.z,wB.w,ai2);
            ar3=fmaf(n.w,wB.z,ar3); ai3=fmaf(n.w,wB.w,ai3);
            // slide window: next block needs xp[k+4..k+6]
            h0 = n.y; h1v = n.z; h2 = n.w;
        }
        float4 mag;
        mag.x = sqrtf(ar0*ar0 + ai0*ai0);
        mag.y = sqrtf(ar1*ar1 + ai1*ai1);
        mag.z = sqrtf(ar2*ar2 + ai2*ai2);
        mag.w = sqrtf(ar3*ar3 + ai3*ai3);
        const int ta = t0 - 2 + tt0;          // zero outside [0,T): feeds SAME zero-pad
        if ((unsigned)(ta + 0) >= T_LEN) mag.x = 0.f;
        if ((unsigned)(ta + 1) >= T_LEN) mag.y = 0.f;
        if ((unsigned)(ta + 2) >= T_LEN) mag.z = 0.f;
        if ((unsigned)(ta + 3) >= T_LEN) mag.w = 0.f;
        *reinterpret_cast<float4*>(cwtb + s * RS + tt0) = mag;
    }
    __syncthreads();

    // per-channel weights -> registers (after stage1 to limit live range)
    float W1r[9], W2r[9];
    #pragma unroll
    for (int k = 0; k < 9; ++k) { W1r[k] = w1[c * 9 + k]; W2r[k] = w2[c * 9 + k]; }
    const float B1v = b1[c], B2v = b2[c];
    const float blend = 1.f / (1.f + expf(-blend_logit[0]));

    // ---- stage 2: h1 = GELU(dwconv1(cwt * corr)) over tt1 in [0, TW+2) ----
    float* h1b = reg2;                        // reuse wavelet region
    for (int item = tid; item < NS * (TW + 2); item += BT) {
        int s   = item / (TW + 2);
        int tt1 = item - s * (TW + 2);
        int ta  = t0 - 1 + tt1;
        float v = 0.f;
        if ((unsigned)ta < T_LEN) {
            float acc = B1v;
            #pragma unroll
            for (int ds = 0; ds < 3; ++ds) {
                int s2 = s + ds - 1;
                if ((unsigned)s2 < NS) {
                    float cr = corr[s2];
                    const float* row = cwtb + s2 * RS + tt1;
                    acc = fmaf(row[0] * cr, W1r[ds * 3 + 0], acc);
                    acc = fmaf(row[1] * cr, W1r[ds * 3 + 1], acc);
                    acc = fmaf(row[2] * cr, W1r[ds * 3 + 2], acc);
                }
            }
            v = gelu_exact(acc);
        }
        h1b[s * RS + tt1] = v;
    }
    __syncthreads();

    // ---- stage 3: h2 = GELU(dwconv2(h1)); blend; mean ratio; out = x * mean ----
    for (int tt2 = tid; tt2 < TW; tt2 += BT) {
        float racc = 0.f;
        #pragma unroll
        for (int s = 0; s < NS; ++s) {
            float acc = B2v;
            #pragma unroll
            for (int ds = 0; ds < 3; ++ds) {
                int s2 = s + ds - 1;
                if ((unsigned)s2 < NS) {
                    const float* row = h1b + s2 * RS + tt2;
                    acc = fmaf(row[0], W2r[ds * 3 + 0], acc);
                    acc = fmaf(row[1], W2r[ds * 3 + 1], acc);
                    acc = fmaf(row[2], W2r[ds * 3 + 2], acc);
                }
            }
            float h2v = gelu_exact(acc);
            float cv  = cwtb[s * RS + tt2 + 2];
            racc += (blend * h2v + (1.f - blend) * cv) / (cv + 1e-8f);
        }
        int t = t0 + tt2;
        if (t < T_LEN)
            out[(size_t)bc * T_LEN + t] = xw[tt2 + XBASE] * racc * (1.f / 16.f);
    }
}

extern "C" void kernel_launch(void* const* d_in, const int* in_sizes, int n_in,
                              void* d_out, int out_size, void* d_ws, size_t ws_size,
                              hipStream_t stream) {
    const float* x  = (const float*)d_in[0];
    const float* w1 = (const float*)d_in[1];
    const float* b1 = (const float*)d_in[2];
    const float* w2 = (const float*)d_in[3];
    const float* b2 = (const float*)d_in[4];
    const float* bl = (const float*)d_in[5];
    const float* ls = (const float*)d_in[6];
    float* out = (float*)d_out;

    float* wavg = (float*)d_ws;   // TOTW floats

    hipLaunchKernelGGL(wavelet_init, dim3(14), dim3(256), 0, stream, wavg);

    dim3 grid(NTILES, BATCH * CH);
    hipLaunchKernelGGL(wlsc_main, grid, dim3(BT), 0, stream,
                       x, w1, b1, w2, b2, bl, ls, wavg, out);
}

// Round 4
// 537.475 us; speedup vs baseline: 3.1615x; 1.1860x over previous
//
#include <hip/hip_runtime.h>
#include <math.h>

// Problem constants
#define NS     16
#define T_LEN  8192
#define BATCH  8
#define CH     32

// Tiling: TW outputs/block; cwt tile = TW+4 = 256 = 64 lanes * 4 outputs
#define TW     252
#define BT     256
#define NTILES 33          // ceil(8192/252)
#define RS     256         // row stride for cwt/h1 tiles in LDS
#define XWIN   776         // x window: covers [t0-262, t0+514)
#define XBASE  262

// Per-scale constants (match wavelet_init's math; validated rounds 1-2)
constexpr int LT[NS]    = {13,17,23,31,41,55,75,103,139,191,259,351,477,513,513,513};
constexpr int PADT[NS]  = {6,8,11,15,20,27,37,51,69,95,129,175,238,256,256,256};
// j0 = (3 - pad) & 3  -> leading zero-taps so the sliding-window x load is 16B aligned
constexpr int J0T[NS]   = {1,3,0,0,3,0,2,0,2,0,2,0,1,3,3,3};
// Lpad = align4(j0 + L)  (trailing zero-taps)
constexpr int LPADT[NS] = {16,20,24,32,44,56,80,104,144,192,264,352,480,516,516,516};
// packed float offsets (2*Lpad prefix) — all multiples of 8 -> 32B-aligned rows
constexpr int WOFFT[NS] = {0,32,72,120,184,272,384,544,752,1040,1424,1952,2656,3616,4648,5680};
#define TOTW      6712     // total packed floats
#define TOTSLOTS  3356     // packed float2 slots

// LPT balance of scales over 4 waves: tap sums 826/833/827/828
constexpr int USCALE[NS] = {13,10,4,0, 14,9,6,3,2, 15,8,7,5,1, 12,11};
constexpr int UOFF[5]    = {0,4,9,14,16};

__device__ __forceinline__ float gelu_exact(float v) {
    return 0.5f * v * (1.0f + erff(v * 0.70710678118654752440f));
}

// Regenerate packed wavelet table every launch (d_ws re-poisoned each call).
// Packed layout: per scale s, LPADT[s] float2 slots at WOFFT[s]; slot k holds
// tap j = k - J0T[s] (zeros outside [0,L)). Double precision mirrors numpy.
__global__ void wavelet_init(float* __restrict__ wavg) {
    int idx0   = blockIdx.x * blockDim.x + threadIdx.x;
    int stride = gridDim.x * blockDim.x;
    for (int idx = idx0; idx < TOTSLOTS; idx += stride) {
        int s = 0;
        while (s < NS - 1 && idx >= (WOFFT[s + 1] >> 1)) ++s;
        int k = idx - (WOFFT[s] >> 1);
        int L = LT[s];
        int j = k - J0T[s];
        float r = 0.f, im = 0.f;
        if (j >= 0 && j < L) {
            double e  = (s == NS - 1) ? log10(200.0)
                                      : (log10(2.0) + (double)s * ((log10(200.0) - log10(2.0)) / 15.0));
            double sc = pow(10.0, e);
            double lo = -(double)((L + 1) / 2);     // Python (-L)//2, L odd
            double hi =  (double)(L / 2);
            double st = (hi - lo) / (double)(L - 1);
            double t  = (j == L - 1) ? hi : (lo + (double)j * st);
            double ts = t / sc;
            double nm = 1.0 / (pow(M_PI, 0.25) * sqrt(sc));
            double g  = nm * exp(-(ts * ts) * 0.5);
            r  = (float)(g * cos(5.0 * ts));
            im = (float)(g * sin(5.0 * ts));
        }
        wavg[2 * idx]     = r;
        wavg[2 * idx + 1] = im;
    }
}

__global__ __launch_bounds__(BT, 4) void wlsc_main(
    const float* __restrict__ x,
    const float* __restrict__ w1, const float* __restrict__ b1,
    const float* __restrict__ w2, const float* __restrict__ b2,
    const float* __restrict__ blend_logit,
    const float* __restrict__ lsc,
    const float* __restrict__ wavg,
    float* __restrict__ out)
{
    __shared__ float xw[XWIN];
    __shared__ float cwtb[NS * RS];
    __shared__ float h1b[NS * RS];
    __shared__ float corr[NS];

    const int tid  = threadIdx.x;
    const int tile = blockIdx.x;
    const int bc   = blockIdx.y;
    const int t0   = tile * TW;
    const int c    = bc & (CH - 1);
    const float* xbc = x + (size_t)bc * T_LEN;

    if (tid < NS) corr[tid] = expf(lsc[tid]);

    // stage x window (reflect pad) into LDS
    for (int i = tid; i < XWIN; i += BT) {
        int gi = t0 - XBASE + i;
        if (gi < 0)      gi = -gi;
        if (gi >= T_LEN) gi = 2 * T_LEN - 2 - gi;
        xw[i] = xbc[gi];
    }
    __syncthreads();

    // ---- stage 1: CWT magnitudes. One wave = one scale at a time;
    // lane computes 4 consecutive outputs tt0..tt0+3 via sliding window.
    // Wavelet taps: wave-uniform addresses -> scalar loads (s_load), NOT LDS:
    // keeps the per-CU LDS pipe for the lane-strided x reads only. ----
    const int wid  = tid >> 6;
    const int lane = tid & 63;
    const int tt0  = lane << 2;
    const int u0 = __builtin_amdgcn_readfirstlane(UOFF[wid]);
    const int u1 = __builtin_amdgcn_readfirstlane(UOFF[wid + 1]);
    for (int u = u0; u < u1; ++u) {
        const int s   = __builtin_amdgcn_readfirstlane(USCALE[u]);
        const int pj  = __builtin_amdgcn_readfirstlane(PADT[s] + J0T[s]);
        const int nb  = __builtin_amdgcn_readfirstlane(LPADT[s] >> 2);
        const float* wp = wavg + __builtin_amdgcn_readfirstlane(WOFFT[s]);
        const float* xp = xw + (tt0 + 260 - pj);   // x for (tap k, out m) = xp[k+m]
        float ar0=0.f,ar1=0.f,ar2=0.f,ar3=0.f, ai0=0.f,ai1=0.f,ai2=0.f,ai3=0.f;
        float h0 = xp[0], h1v = xp[1], h2 = xp[2];
        #pragma unroll 2
        for (int b = 0; b < nb; ++b) {
            const int k = b << 2;
            float4 n  = *reinterpret_cast<const float4*>(xp + k + 3);  // LDS, 16B aligned
            float4 wA = *reinterpret_cast<const float4*>(wp + 2 * k);      // uniform -> s_load
            float4 wB = *reinterpret_cast<const float4*>(wp + 2 * k + 4);  // uniform -> s_load
            // tap k
            ar0=fmaf(h0 ,wA.x,ar0); ai0=fmaf(h0 ,wA.y,ai0);
            ar1=fmaf(h1v,wA.x,ar1); ai1=fmaf(h1v,wA.y,ai1);
            ar2=fmaf(h2 ,wA.x,ar2); ai2=fmaf(h2 ,wA.y,ai2);
            ar3=fmaf(n.x,wA.x,ar3); ai3=fmaf(n.x,wA.y,ai3);
            // tap k+1
            ar0=fmaf(h1v,wA.z,ar0); ai0=fmaf(h1v,wA.w,ai0);
            ar1=fmaf(h2 ,wA.z,ar1); ai1=fmaf(h2 ,wA.w,ai1);
            ar2=fmaf(n.x,wA.z,ar2); ai2=fmaf(n.x,wA.w,ai2);
            ar3=fmaf(n.y,wA.z,ar3); ai3=fmaf(n.y,wA.w,ai3);
            // tap k+2
            ar0=fmaf(h2 ,wB.x,ar0); ai0=fmaf(h2 ,wB.y,ai0);
            ar1=fmaf(n.x,wB.x,ar1); ai1=fmaf(n.x,wB.y,ai1);
            ar2=fmaf(n.y,wB.x,ar2); ai2=fmaf(n.y,wB.y,ai2);
            ar3=fmaf(n.z,wB.x,ar3); ai3=fmaf(n.z,wB.y,ai3);
            // tap k+3
            ar0=fmaf(n.x,wB.z,ar0); ai0=fmaf(n.x,wB.w,ai0);
            ar1=fmaf(n.y,wB.z,ar1); ai1=fmaf(n.y,wB.w,ai1);
            ar2=fmaf(n.z,wB.z,ar2); ai2=fmaf(n.z,wB.w,ai2);
            ar3=fmaf(n.w,wB.z,ar3); ai3=fmaf(n.w,wB.w,ai3);
            // slide window: next block needs xp[k+4..k+6]
            h0 = n.y; h1v = n.z; h2 = n.w;
        }
        float4 mag;
        mag.x = sqrtf(ar0*ar0 + ai0*ai0);
        mag.y = sqrtf(ar1*ar1 + ai1*ai1);
        mag.z = sqrtf(ar2*ar2 + ai2*ai2);
        mag.w = sqrtf(ar3*ar3 + ai3*ai3);
        const int ta = t0 - 2 + tt0;          // zero outside [0,T): feeds SAME zero-pad
        if ((unsigned)(ta + 0) >= T_LEN) mag.x = 0.f;
        if ((unsigned)(ta + 1) >= T_LEN) mag.y = 0.f;
        if ((unsigned)(ta + 2) >= T_LEN) mag.z = 0.f;
        if ((unsigned)(ta + 3) >= T_LEN) mag.w = 0.f;
        *reinterpret_cast<float4*>(cwtb + s * RS + tt0) = mag;
    }
    __syncthreads();

    // per-channel weights -> registers (after stage1 to limit live range)
    float W1r[9], W2r[9];
    #pragma unroll
    for (int k = 0; k < 9; ++k) { W1r[k] = w1[c * 9 + k]; W2r[k] = w2[c * 9 + k]; }
    const float B1v = b1[c], B2v = b2[c];
    const float blend = 1.f / (1.f + expf(-blend_logit[0]));

    // ---- stage 2: h1 = GELU(dwconv1(cwt * corr)) over tt1 in [0, TW+2) ----
    for (int item = tid; item < NS * (TW + 2); item += BT) {
        int s   = item / (TW + 2);
        int tt1 = item - s * (TW + 2);
        int ta  = t0 - 1 + tt1;
        float v = 0.f;
        if ((unsigned)ta < T_LEN) {
            float acc = B1v;
            #pragma unroll
            for (int ds = 0; ds < 3; ++ds) {
                int s2 = s + ds - 1;
                if ((unsigned)s2 < NS) {
                    float cr = corr[s2];
                    const float* row = cwtb + s2 * RS + tt1;
                    acc = fmaf(row[0] * cr, W1r[ds * 3 + 0], acc);
                    acc = fmaf(row[1] * cr, W1r[ds * 3 + 1], acc);
                    acc = fmaf(row[2] * cr, W1r[ds * 3 + 2], acc);
                }
            }
            v = gelu_exact(acc);
        }
        h1b[s * RS + tt1] = v;
    }
    __syncthreads();

    // ---- stage 3: h2 = GELU(dwconv2(h1)); blend; mean ratio; out = x * mean ----
    for (int tt2 = tid; tt2 < TW; tt2 += BT) {
        float racc = 0.f;
        #pragma unroll
        for (int s = 0; s < NS; ++s) {
            float acc = B2v;
            #pragma unroll
            for (int ds = 0; ds < 3; ++ds) {
                int s2 = s + ds - 1;
                if ((unsigned)s2 < NS) {
                    const float* row = h1b + s2 * RS + tt2;
                    acc = fmaf(row[0], W2r[ds * 3 + 0], acc);
                    acc = fmaf(row[1], W2r[ds * 3 + 1], acc);
                    acc = fmaf(row[2], W2r[ds * 3 + 2], acc);
                }
            }
            float h2v = gelu_exact(acc);
            float cv  = cwtb[s * RS + tt2 + 2];
            racc += (blend * h2v + (1.f - blend) * cv) / (cv + 1e-8f);
        }
        int t = t0 + tt2;
        if (t < T_LEN)
            out[(size_t)bc * T_LEN + t] = xw[tt2 + XBASE] * racc * (1.f / 16.f);
    }
}

extern "C" void kernel_launch(void* const* d_in, const int* in_sizes, int n_in,
                              void* d_out, int out_size, void* d_ws, size_t ws_size,
                              hipStream_t stream) {
    const float* x  = (const float*)d_in[0];
    const float* w1 = (const float*)d_in[1];
    const float* b1 = (const float*)d_in[2];
    const float* w2 = (const float*)d_in[3];
    const float* b2 = (const float*)d_in[4];
    const float* bl = (const float*)d_in[5];
    const float* ls = (const float*)d_in[6];
    float* out = (float*)d_out;

    float* wavg = (float*)d_ws;   // TOTW floats

    hipLaunchKernelGGL(wavelet_init, dim3(14), dim3(256), 0, stream, wavg);

    dim3 grid(NTILES, BATCH * CH);
    hipLaunchKernelGGL(wlsc_main, grid, dim3(BT), 0, stream,
                       x, w1, b1, w2, b2, bl, ls, wavg, out);
}

// Round 7
// 353.039 us; speedup vs baseline: 4.8131x; 1.5224x over previous
//
#include <hip/hip_runtime.h>
#include <math.h>

// Problem constants
#define NS     16
#define T_LEN  8192
#define BATCH  8
#define CH     32

// Tiling
#define TW     252        // outputs per block
#define BT     256
#define NTILES 33         // ceil(8192/252)
#define RS     260        // cwt/h1 row stride (260%32=4 -> s-rows spread banks)
#define NKC    33         // K chunks of 16: shared tap window k' in [0,528)
#define XWELEM 784        // x window elems: u = tt + k', tt<256, k'<528
#define XCS    792        // copy stride (x2B = 1584 B, 16B-aligned)
#define NFRAG  (NKC*512)  // wavelet fragment f16 count per stream (33 KB)

typedef _Float16 f16x8 __attribute__((ext_vector_type(8)));
typedef float    f32x16 __attribute__((ext_vector_type(16)));

// Per-scale constants (validated rounds 1-4)
constexpr int LT[NS]   = {13,17,23,31,41,55,75,103,139,191,259,351,477,513,513,513};
constexpr int PADT[NS] = {6,8,11,15,20,27,37,51,69,95,129,175,238,256,256,256};

__device__ __forceinline__ float gelu_exact(float v) {
    return 0.5f * v * (1.0f + erff(v * 0.70710678118654752440f));
}

// Regenerate wavelet B-fragment streams (hi + lo split-f16) every launch.
// Element (kc, lane, j) at [kc*512 + lane*8 + j] holds B[k=8*(lane>>5)+j][n=lane&31]
// for chunk kc: tap of scale s=n>>1 (n even=real, odd=imag) at
// j_tap = (kc*16 + k) - 256 + pad_s.  w_f32 = hi + lo with hi=(f16)w_f32.
__global__ void wavelet_init(_Float16* __restrict__ whi, _Float16* __restrict__ wlo) {
    int idx0   = blockIdx.x * blockDim.x + threadIdx.x;
    int stride = gridDim.x * blockDim.x;
    for (int idx = idx0; idx < NFRAG; idx += stride) {
        int kc   = idx >> 9;
        int r    = idx & 511;
        int lane = r >> 3;
        int j    = r & 7;
        int n    = lane & 31;
        int h    = lane >> 5;
        int kp   = kc * 16 + 8 * h + j;      // k' in [0,528+15]
        int s    = n >> 1;
        int ri   = n & 1;
        int L    = LT[s];
        int jt   = kp - 256 + PADT[s];
        float wf = 0.f;
        if (jt >= 0 && jt < L) {
            double e  = (s == NS - 1) ? log10(200.0)
                                      : (log10(2.0) + (double)s * ((log10(200.0) - log10(2.0)) / 15.0));
            double sc = pow(10.0, e);
            double lo = -(double)((L + 1) / 2);   // Python (-L)//2, L odd
            double hi =  (double)(L / 2);
            double st = (hi - lo) / (double)(L - 1);
            double t  = (jt == L - 1) ? hi : (lo + (double)jt * st);
            double ts = t / sc;
            double nm = 1.0 / (pow(M_PI, 0.25) * sqrt(sc));
            double g  = nm * exp(-(ts * ts) * 0.5);
            wf = (float)(ri ? (g * sin(5.0 * ts)) : (g * cos(5.0 * ts)));
        }
        _Float16 hv = (_Float16)wf;
        whi[idx] = hv;
        wlo[idx] = (_Float16)(wf - (float)hv);
    }
}

__global__ __launch_bounds__(BT, 3) void wlsc_main(
    const float* __restrict__ x,
    const float* __restrict__ w1, const float* __restrict__ b1,
    const float* __restrict__ w2, const float* __restrict__ b2,
    const float* __restrict__ blend_logit,
    const float* __restrict__ lsc,
    const _Float16* __restrict__ wfh,
    const _Float16* __restrict__ wfl,
    float* __restrict__ out)
{
    __shared__ float cwtb[NS * RS];                       // 16.6 KB
    __shared__ __align__(16) char ubuf[16 * XCS * 2];     // xc hi+lo (stage1) / h1b (25.3 KB)
    __shared__ float corr[NS];
    _Float16* xch = (_Float16*)ubuf;          // 8 shifted copies, [8][XCS]
    _Float16* xcl = xch + 8 * XCS;            // lo copies
    float*    h1b = (float*)ubuf;             // stages 2/3 overlay (16.6 KB <= 25.3 KB)

    const int tid  = threadIdx.x;
    const int tile = blockIdx.x;
    const int bc   = blockIdx.y;
    const int t0   = tile * TW;
    const int c    = bc & (CH - 1);
    const float* xbc = x + (size_t)bc * T_LEN;

    if (tid < NS) corr[tid] = expf(lsc[tid]);

    // ---- stage x window as split-f16, 8 shifted copies: x[t0-258+u+cp]
    // (shift makes every lane's 8-f16 A-frag read 16B-aligned) ----
    for (int i = tid; i < 8 * XWELEM; i += BT) {
        int cp = i / XWELEM;
        int u  = i - cp * XWELEM;
        int g  = t0 - 258 + u + cp;
        if (g < 0)      g = -g;
        if (g >= T_LEN) g = 2 * T_LEN - 2 - g;
        float xv = xbc[g];
        _Float16 hv = (_Float16)xv;
        xch[cp * XCS + u] = hv;
        xcl[cp * XCS + u] = (_Float16)(xv - (float)hv);
    }
    __syncthreads();

    // ---- stage 1: CWT via mfma_f32_32x32x16_f16, split-f16 3-product scheme:
    // D = Ah*Bh + Ah*Bl + Al*Bh  (rel err ~2^-22; Al*Bl negligible).
    // D[m=tt in m-tile][n=2s+ri] = sum_k' B[k'][n] * x[t0-258+tt+k'].
    // Wave wid owns m-tiles {2wid, 2wid+1}; 33 K-chunks of 16. ----
    const int lane = tid & 63;
    const int wid  = tid >> 6;
    const int m    = lane & 31;
    const int h    = lane >> 5;
    f32x16 acc0, acc1;
    #pragma unroll
    for (int i = 0; i < 16; ++i) { acc0[i] = 0.f; acc1[i] = 0.f; }

    const int aoff = (m & 7) * XCS + ((m & ~7) + 8 * h);
    const _Float16* xbh = xch + aoff;
    const _Float16* xbl = xcl + aoff;
    const int mt0 = 2 * wid, mt1 = 2 * wid + 1;
    const f16x8* wh = reinterpret_cast<const f16x8*>(wfh);
    const f16x8* wl = reinterpret_cast<const f16x8*>(wfl);
    #pragma unroll 3
    for (int kc = 0; kc < NKC; ++kc) {
        f16x8 bh = wh[kc * 64 + lane];                                   // global, L2-hit
        f16x8 bl = wl[kc * 64 + lane];
        f16x8 ah0 = *reinterpret_cast<const f16x8*>(xbh + mt0 * 32 + kc * 16);  // LDS b128
        f16x8 al0 = *reinterpret_cast<const f16x8*>(xbl + mt0 * 32 + kc * 16);
        f16x8 ah1 = *reinterpret_cast<const f16x8*>(xbh + mt1 * 32 + kc * 16);
        f16x8 al1 = *reinterpret_cast<const f16x8*>(xbl + mt1 * 32 + kc * 16);
        acc0 = __builtin_amdgcn_mfma_f32_32x32x16_f16(ah0, bh, acc0, 0, 0, 0);
        acc0 = __builtin_amdgcn_mfma_f32_32x32x16_f16(ah0, bl, acc0, 0, 0, 0);
        acc0 = __builtin_amdgcn_mfma_f32_32x32x16_f16(al0, bh, acc0, 0, 0, 0);
        acc1 = __builtin_amdgcn_mfma_f32_32x32x16_f16(ah1, bh, acc1, 0, 0, 0);
        acc1 = __builtin_amdgcn_mfma_f32_32x32x16_f16(ah1, bl, acc1, 0, 0, 0);
        acc1 = __builtin_amdgcn_mfma_f32_32x32x16_f16(al1, bh, acc1, 0, 0, 0);
    }

    // magnitudes: pair (r,i) across lanes n, n^1; even-n lanes store to cwtb.
    // C/D layout: col=lane&31, row=(reg&3)+8*(reg>>2)+4*(lane>>5)  [m74/m101]
    const int s_mine = (lane & 31) >> 1;
    #pragma unroll
    for (int half = 0; half < 2; ++half) {
        f32x16& acc = half ? acc1 : acc0;
        const int mt = half ? mt1 : mt0;
        #pragma unroll
        for (int g = 0; g < 4; ++g) {
            float4 mag;
            #pragma unroll
            for (int e = 0; e < 4; ++e) {
                float cr = acc[4 * g + e];
                float ci = __shfl_xor(cr, 1);
                float mg = sqrtf(cr * cr + ci * ci);
                int tt = mt * 32 + 8 * g + 4 * h + e;
                int ta = t0 - 2 + tt;                 // zero outside [0,T)
                if ((unsigned)ta >= T_LEN) mg = 0.f;
                (&mag.x)[e] = mg;
            }
            if ((lane & 1) == 0)
                *reinterpret_cast<float4*>(cwtb + s_mine * RS + mt * 32 + 8 * g + 4 * h) = mag;
        }
    }
    __syncthreads();

    // per-channel weights -> registers
    float W1r[9], W2r[9];
    #pragma unroll
    for (int k = 0; k < 9; ++k) { W1r[k] = w1[c * 9 + k]; W2r[k] = w2[c * 9 + k]; }
    const float B1v = b1[c], B2v = b2[c];
    const float blend = 1.f / (1.f + expf(-blend_logit[0]));

    // ---- stage 2: h1 = GELU(dwconv1(cwt * corr)) over tt1 in [0, TW+2) ----
    for (int item = tid; item < NS * (TW + 2); item += BT) {
        int s   = item / (TW + 2);
        int tt1 = item - s * (TW + 2);
        int ta  = t0 - 1 + tt1;
        float v = 0.f;
        if ((unsigned)ta < T_LEN) {
            float acc = B1v;
            #pragma unroll
            for (int ds = 0; ds < 3; ++ds) {
                int s2 = s + ds - 1;
                if ((unsigned)s2 < NS) {
                    float cr = corr[s2];
                    const float* row = cwtb + s2 * RS + tt1;
                    acc = fmaf(row[0] * cr, W1r[ds * 3 + 0], acc);
                    acc = fmaf(row[1] * cr, W1r[ds * 3 + 1], acc);
                    acc = fmaf(row[2] * cr, W1r[ds * 3 + 2], acc);
                }
            }
            v = gelu_exact(acc);
        }
        h1b[s * RS + tt1] = v;
    }
    __syncthreads();

    // ---- stage 3: h2 = GELU(dwconv2(h1)); blend; mean ratio; out = x * mean ----
    for (int tt2 = tid; tt2 < TW; tt2 += BT) {
        float racc = 0.f;
        #pragma unroll
        for (int s = 0; s < NS; ++s) {
            float acc = B2v;
            #pragma unroll
            for (int ds = 0; ds < 3; ++ds) {
                int s2 = s + ds - 1;
                if ((unsigned)s2 < NS) {
                    const float* row = h1b + s2 * RS + tt2;
                    acc = fmaf(row[0], W2r[ds * 3 + 0], acc);
                    acc = fmaf(row[1], W2r[ds * 3 + 1], acc);
                    acc = fmaf(row[2], W2r[ds * 3 + 2], acc);
                }
            }
            float h2v = gelu_exact(acc);
            float cv  = cwtb[s * RS + tt2 + 2];
            racc += (blend * h2v + (1.f - blend) * cv) / (cv + 1e-8f);
        }
        int t = t0 + tt2;
        if (t < T_LEN)
            out[(size_t)bc * T_LEN + t] = xbc[t] * racc * (1.f / 16.f);
    }
}

extern "C" void kernel_launch(void* const* d_in, const int* in_sizes, int n_in,
                              void* d_out, int out_size, void* d_ws, size_t ws_size,
                              hipStream_t stream) {
    const float* x  = (const float*)d_in[0];
    const float* w1 = (const float*)d_in[1];
    const float* b1 = (const float*)d_in[2];
    const float* w2 = (const float*)d_in[3];
    const float* b2 = (const float*)d_in[4];
    const float* bl = (const float*)d_in[5];
    const float* ls = (const float*)d_in[6];
    float* out = (float*)d_out;

    _Float16* whi = (_Float16*)d_ws;          // NFRAG f16
    _Float16* wlo = whi + NFRAG;              // NFRAG f16 (offset 33792 B, 16B-aligned)

    hipLaunchKernelGGL(wavelet_init, dim3(68), dim3(256), 0, stream, whi, wlo);

    dim3 grid(NTILES, BATCH * CH);
    hipLaunchKernelGGL(wlsc_main, grid, dim3(BT), 0, stream,
                       x, w1, b1, w2, b2, bl, ls, whi, wlo, out);
}

// Round 10
// 295.295 us; speedup vs baseline: 5.7543x; 1.1955x over previous
//
#include <hip/hip_runtime.h>
#include <math.h>

// Problem constants
#define NS     16
#define T_LEN  8192
#define BATCH  8
#define CH     32

// Tiling
#define TW     252        // outputs per block
#define BT     256
#define NTILES 33         // ceil(8192/252)
#define RS     260        // cwt row stride (dwords; 260%32=4 spreads s-rows over banks)
#define H1S    256        // h1 row stride (dwords)
#define NKC    33         // K chunks of 16: shared tap window k' in [0,528)
#define XWELEM 784        // x window elems per copy
#define XCS    792        // copy stride in f16 elems (1584 B, 16B-aligned)
#define NCPY   4          // shifted copies (b64 alignment: frag start ≡ 0 mod 4)
#define NFRAG  (NKC*512)  // wavelet fragment f16 count per stream

typedef _Float16 f16x4 __attribute__((ext_vector_type(4)));
typedef _Float16 f16x8 __attribute__((ext_vector_type(8)));
typedef float    f32x16 __attribute__((ext_vector_type(16)));

// Per-scale constants (validated rounds 1-7)
constexpr int LT[NS]   = {13,17,23,31,41,55,75,103,139,191,259,351,477,513,513,513};
constexpr int PADT[NS] = {6,8,11,15,20,27,37,51,69,95,129,175,238,256,256,256};

__device__ __forceinline__ float gelu_exact(float v) {
    return 0.5f * v * (1.0f + erff(v * 0.70710678118654752440f));
}

// Regenerate wavelet B-fragment streams (hi + lo split-f16) every launch.
// Element (kc, lane, j) at [kc*512 + lane*8 + j] holds B[k=8*(lane>>5)+j][n=lane&31]
// for chunk kc: tap of scale s=n>>1 (n even=real, odd=imag) at
// j_tap = (kc*16 + k) - 256 + pad_s.  w_f32 = hi + lo with hi=(f16)w_f32.
__global__ void wavelet_init(_Float16* __restrict__ whi, _Float16* __restrict__ wlo) {
    int idx0   = blockIdx.x * blockDim.x + threadIdx.x;
    int stride = gridDim.x * blockDim.x;
    for (int idx = idx0; idx < NFRAG; idx += stride) {
        int kc   = idx >> 9;
        int r    = idx & 511;
        int lane = r >> 3;
        int j    = r & 7;
        int n    = lane & 31;
        int h    = lane >> 5;
        int kp   = kc * 16 + 8 * h + j;      // k' in [0,528+15]
        int s    = n >> 1;
        int ri   = n & 1;
        int L    = LT[s];
        int jt   = kp - 256 + PADT[s];
        float wf = 0.f;
        if (jt >= 0 && jt < L) {
            double e  = (s == NS - 1) ? log10(200.0)
                                      : (log10(2.0) + (double)s * ((log10(200.0) - log10(2.0)) / 15.0));
            double sc = pow(10.0, e);
            double lo = -(double)((L + 1) / 2);   // Python (-L)//2, L odd
            double hi =  (double)(L / 2);
            double st = (hi - lo) / (double)(L - 1);
            double t  = (jt == L - 1) ? hi : (lo + (double)jt * st);
            double ts = t / sc;
            double nm = 1.0 / (pow(M_PI, 0.25) * sqrt(sc));
            double g  = nm * exp(-(ts * ts) * 0.5);
            wf = (float)(ri ? (g * sin(5.0 * ts)) : (g * cos(5.0 * ts)));
        }
        _Float16 hv = (_Float16)wf;
        whi[idx] = hv;
        wlo[idx] = (_Float16)(wf - (float)hv);
    }
}

__global__ __launch_bounds__(BT, 4) void wlsc_main(
    const float* __restrict__ x,
    const float* __restrict__ w1, const float* __restrict__ b1,
    const float* __restrict__ w2, const float* __restrict__ b2,
    const float* __restrict__ blend_logit,
    const float* __restrict__ lsc,
    const _Float16* __restrict__ wfh,
    const _Float16* __restrict__ wfl,
    float* __restrict__ out)
{
    __shared__ float cwtb[NS * RS];                     // 16640 B
    __shared__ __align__(16) char ubuf[NS * H1S * 4];   // 16384 B: xc (stage1) / h1b (2+)
    __shared__ float corr[NS];
    _Float16* xch = (_Float16*)ubuf;          // [NCPY][XCS] hi copies (6336 B)
    _Float16* xcl = xch + NCPY * XCS;         // [NCPY][XCS] lo copies (6336 B)
    float*    h1b = (float*)ubuf;             // overlay for stages 2/3

    const int tid  = threadIdx.x;
    const int tile = blockIdx.x;
    const int bc   = blockIdx.y;
    const int t0   = tile * TW;
    const int c    = bc & (CH - 1);
    const float* xbc = x + (size_t)bc * T_LEN;

    if (tid < NS) corr[tid] = expf(lsc[tid]);

    // ---- stage x window as split-f16 into 4 shifted copies:
    // xc[cp][u] = x[t0-258+u+cp]; one global load per element v, 4 guarded stores ----
    for (int v = tid; v < XWELEM + NCPY; v += BT) {
        int g = t0 - 258 + v;
        if (g < 0)      g = -g;
        if (g >= T_LEN) g = 2 * T_LEN - 2 - g;
        float xv = xbc[g];
        _Float16 hv = (_Float16)xv;
        _Float16 lv = (_Float16)(xv - (float)hv);
        #pragma unroll
        for (int cp = 0; cp < NCPY; ++cp) {
            int idx = v - cp;
            if ((unsigned)idx < XWELEM) {
                xch[cp * XCS + idx] = hv;
                xcl[cp * XCS + idx] = lv;
            }
        }
    }
    __syncthreads();

    // ---- stage 1: CWT via mfma_f32_32x32x16_f16, split-f16 3-product scheme:
    // D = Ah*Bh + Ah*Bl + Al*Bh.  A-frag = two ds_read_b64 (8B-aligned via copy
    // cp = m&3).  Wave wid owns m-tiles {2wid, 2wid+1}; 33 K-chunks of 16. ----
    const int lane = tid & 63;
    const int wid  = tid >> 6;
    const int m    = lane & 31;
    const int h    = lane >> 5;
    const int mt0  = 2 * wid, mt1 = 2 * wid + 1;
    f32x16 acc0, acc1;
    #pragma unroll
    for (int i = 0; i < 16; ++i) { acc0[i] = 0.f; acc1[i] = 0.f; }

    const int abase = (m & 3) * XCS + ((m & ~3) + 8 * h);
    const _Float16* pah = xch + abase;
    const _Float16* pal = xcl + abase;
    const f16x8* wh = reinterpret_cast<const f16x8*>(wfh);
    const f16x8* wl = reinterpret_cast<const f16x8*>(wfl);
    #pragma unroll 3
    for (int kc = 0; kc < NKC; ++kc) {
        f16x8 bh = wh[kc * 64 + lane];          // global, L1/L2-hit
        f16x8 bl = wl[kc * 64 + lane];
        const int o0 = mt0 * 32 + kc * 16;
        const int o1 = mt1 * 32 + kc * 16;
        f16x4 ah0a = *(const f16x4*)(pah + o0), ah0b = *(const f16x4*)(pah + o0 + 4);
        f16x4 al0a = *(const f16x4*)(pal + o0), al0b = *(const f16x4*)(pal + o0 + 4);
        f16x4 ah1a = *(const f16x4*)(pah + o1), ah1b = *(const f16x4*)(pah + o1 + 4);
        f16x4 al1a = *(const f16x4*)(pal + o1), al1b = *(const f16x4*)(pal + o1 + 4);
        f16x8 ah0 = __builtin_shufflevector(ah0a, ah0b, 0,1,2,3,4,5,6,7);
        f16x8 al0 = __builtin_shufflevector(al0a, al0b, 0,1,2,3,4,5,6,7);
        f16x8 ah1 = __builtin_shufflevector(ah1a, ah1b, 0,1,2,3,4,5,6,7);
        f16x8 al1 = __builtin_shufflevector(al1a, al1b, 0,1,2,3,4,5,6,7);
        acc0 = __builtin_amdgcn_mfma_f32_32x32x16_f16(ah0, bh, acc0, 0, 0, 0);
        acc0 = __builtin_amdgcn_mfma_f32_32x32x16_f16(ah0, bl, acc0, 0, 0, 0);
        acc0 = __builtin_amdgcn_mfma_f32_32x32x16_f16(al0, bh, acc0, 0, 0, 0);
        acc1 = __builtin_amdgcn_mfma_f32_32x32x16_f16(ah1, bh, acc1, 0, 0, 0);
        acc1 = __builtin_amdgcn_mfma_f32_32x32x16_f16(ah1, bl, acc1, 0, 0, 0);
        acc1 = __builtin_amdgcn_mfma_f32_32x32x16_f16(al1, bh, acc1, 0, 0, 0);
    }

    // magnitudes: pair (r,i) across lanes n, n^1; even-n lanes store to cwtb.
    // C/D layout: col=lane&31, row=(reg&3)+8*(reg>>2)+4*(lane>>5)  [m74/m101]
    const int s_mine = (lane & 31) >> 1;
    #pragma unroll
    for (int half = 0; half < 2; ++half) {
        f32x16& acc = half ? acc1 : acc0;
        const int mt = half ? mt1 : mt0;
        #pragma unroll
        for (int g = 0; g < 4; ++g) {
            float4 mag;
            #pragma unroll
            for (int e = 0; e < 4; ++e) {
                float cr = acc[4 * g + e];
                float ci = __shfl_xor(cr, 1);
                float mg = sqrtf(cr * cr + ci * ci);
                int tt = mt * 32 + 8 * g + 4 * h + e;
                int ta = t0 - 2 + tt;                 // zero outside [0,T)
                if ((unsigned)ta >= T_LEN) mg = 0.f;
                (&mag.x)[e] = mg;
            }
            if ((lane & 1) == 0)
                *reinterpret_cast<float4*>(cwtb + s_mine * RS + mt * 32 + 8 * g + 4 * h) = mag;
        }
    }
    __syncthreads();

    // per-channel weights -> registers
    float W1r[9], W2r[9];
    #pragma unroll
    for (int k = 0; k < 9; ++k) { W1r[k] = w1[c * 9 + k]; W2r[k] = w2[c * 9 + k]; }
    const float B1v = b1[c], B2v = b2[c];
    const float blend = 1.f / (1.f + expf(-blend_logit[0]));

    // ---- stage 2: h1 = GELU(dwconv1(cwt*corr)). Thread owns column tt1;
    // unrolled s-loop with sliding 3-value row registers (3 LDS reads/s). ----
    if (tid < TW + 2) {
        const int tt1 = tid;
        const int ta  = t0 - 1 + tt1;
        const bool inb = (unsigned)ta < T_LEN;
        float p0 = 0.f, p1 = 0.f, p2 = 0.f;     // row s-1 (pre-scaled by corr)
        float c0, c1, c2;                        // row s
        {
            float cr = corr[0];
            const float* r = cwtb + tt1;
            c0 = r[0] * cr; c1 = r[1] * cr; c2 = r[2] * cr;
        }
        #pragma unroll
        for (int s = 0; s < NS; ++s) {
            float n0 = 0.f, n1 = 0.f, n2 = 0.f;  // row s+1
            if (s + 1 < NS) {
                float cr = corr[s + 1];
                const float* r = cwtb + (s + 1) * RS + tt1;
                n0 = r[0] * cr; n1 = r[1] * cr; n2 = r[2] * cr;
            }
            float acc = B1v;
            acc = fmaf(p0, W1r[0], acc); acc = fmaf(p1, W1r[1], acc); acc = fmaf(p2, W1r[2], acc);
            acc = fmaf(c0, W1r[3], acc); acc = fmaf(c1, W1r[4], acc); acc = fmaf(c2, W1r[5], acc);
            acc = fmaf(n0, W1r[6], acc); acc = fmaf(n1, W1r[7], acc); acc = fmaf(n2, W1r[8], acc);
            h1b[s * H1S + tt1] = inb ? gelu_exact(acc) : 0.f;
            p0 = c0; p1 = c1; p2 = c2;
            c0 = n0; c1 = n1; c2 = n2;
        }
    }
    __syncthreads();

    // ---- stage 3: h2 = GELU(dwconv2(h1)); blend; mean ratio; out = x*mean ----
    if (tid < TW) {
        const int tt2 = tid;
        const int t   = t0 + tt2;
        float racc = 0.f;
        float p0 = 0.f, p1 = 0.f, p2 = 0.f;
        float c0, c1, c2;
        {
            const float* r = h1b + tt2;
            c0 = r[0]; c1 = r[1]; c2 = r[2];
        }
        #pragma unroll
        for (int s = 0; s < NS; ++s) {
            float n0 = 0.f, n1 = 0.f, n2 = 0.f;
            if (s + 1 < NS) {
                const float* r = h1b + (s + 1) * H1S + tt2;
                n0 = r[0]; n1 = r[1]; n2 = r[2];
            }
            float acc = B2v;
            acc = fmaf(p0, W2r[0], acc); acc = fmaf(p1, W2r[1], acc); acc = fmaf(p2, W2r[2], acc);
            acc = fmaf(c0, W2r[3], acc); acc = fmaf(c1, W2r[4], acc); acc = fmaf(c2, W2r[5], acc);
            acc = fmaf(n0, W2r[6], acc); acc = fmaf(n1, W2r[7], acc); acc = fmaf(n2, W2r[8], acc);
            float h2v = gelu_exact(acc);
            float cv  = cwtb[s * RS + tt2 + 2];
            float num = blend * h2v + (1.f - blend) * cv;
            racc += num / (cv + 1e-8f);
            p0 = c0; p1 = c1; p2 = c2;
            c0 = n0; c1 = n1; c2 = n2;
        }
        if (t < T_LEN)
            out[(size_t)bc * T_LEN + t] = xbc[t] * racc * (1.f / 16.f);
    }
}

extern "C" void kernel_launch(void* const* d_in, const int* in_sizes, int n_in,
                              void* d_out, int out_size, void* d_ws, size_t ws_size,
                              hipStream_t stream) {
    const float* x  = (const float*)d_in[0];
    const float* w1 = (const float*)d_in[1];
    const float* b1 = (const float*)d_in[2];
    const float* w2 = (const float*)d_in[3];
    const float* b2 = (const float*)d_in[4];
    const float* bl = (const float*)d_in[5];
    const float* ls = (const float*)d_in[6];
    float* out = (float*)d_out;

    _Float16* whi = (_Float16*)d_ws;          // NFRAG f16
    _Float16* wlo = whi + NFRAG;              // NFRAG f16

    hipLaunchKernelGGL(wavelet_init, dim3(68), dim3(256), 0, stream, whi, wlo);

    dim3 grid(NTILES, BATCH * CH);
    hipLaunchKernelGGL(wlsc_main, grid, dim3(BT), 0, stream,
                       x, w1, b1, w2, b2, bl, ls, whi, wlo, out);
}

// Round 12
// 283.090 us; speedup vs baseline: 6.0024x; 1.0431x over previous
//
#include <hip/hip_runtime.h>
#include <math.h>

// Problem constants
#define NS     16
#define T_LEN  8192
#define BATCH  8
#define CH     32

// Tiling
#define TW     252        // outputs per block
#define BT     256
#define NTILES 33         // ceil(8192/252)
#define RS     260        // cwt row stride (dwords; 260%32=4 spreads s-rows over banks)
#define H1S    256        // h1 row stride (dwords)
#define NKC    33         // K chunks of 16: shared tap window k' in [0,528)
#define XWELEM 784        // x window elems per copy
#define XCS    792        // copy stride in f16 elems (1584 B, 16B-aligned)
#define NCPY   4          // shifted copies (b64 alignment: frag start ≡ 0 mod 4)
#define NFRAG  (NKC*512)  // wavelet fragment f16 count per stream

typedef _Float16 f16x4 __attribute__((ext_vector_type(4)));
typedef _Float16 f16x8 __attribute__((ext_vector_type(8)));
typedef float    f32x16 __attribute__((ext_vector_type(16)));

// Per-scale constants (validated rounds 1-10)
constexpr int LT[NS]   = {13,17,23,31,41,55,75,103,139,191,259,351,477,513,513,513};
constexpr int PADT[NS] = {6,8,11,15,20,27,37,51,69,95,129,175,238,256,256,256};

__device__ __forceinline__ float gelu_exact(float v) {
    return 0.5f * v * (1.0f + erff(v * 0.70710678118654752440f));
}

// Regenerate wavelet B-fragment streams (hi + lo split-f16) every launch.
// Element (kc, lane, j) at [kc*512 + lane*8 + j] holds B[k=8*(lane>>5)+j][n=lane&31]
// for chunk kc: tap of scale s=n>>1 (n even=real, odd=imag) at
// j_tap = (kc*16 + k) - 256 + pad_s.  w_f32 = hi + lo with hi=(f16)w_f32.
__global__ void wavelet_init(_Float16* __restrict__ whi, _Float16* __restrict__ wlo) {
    int idx0   = blockIdx.x * blockDim.x + threadIdx.x;
    int stride = gridDim.x * blockDim.x;
    for (int idx = idx0; idx < NFRAG; idx += stride) {
        int kc   = idx >> 9;
        int r    = idx & 511;
        int lane = r >> 3;
        int j    = r & 7;
        int n    = lane & 31;
        int h    = lane >> 5;
        int kp   = kc * 16 + 8 * h + j;      // k' in [0,528+15]
        int s    = n >> 1;
        int ri   = n & 1;
        int L    = LT[s];
        int jt   = kp - 256 + PADT[s];
        float wf = 0.f;
        if (jt >= 0 && jt < L) {
            double e  = (s == NS - 1) ? log10(200.0)
                                      : (log10(2.0) + (double)s * ((log10(200.0) - log10(2.0)) / 15.0));
            double sc = pow(10.0, e);
            double lo = -(double)((L + 1) / 2);   // Python (-L)//2, L odd
            double hi =  (double)(L / 2);
            double st = (hi - lo) / (double)(L - 1);
            double t  = (jt == L - 1) ? hi : (lo + (double)jt * st);
            double ts = t / sc;
            double nm = 1.0 / (pow(M_PI, 0.25) * sqrt(sc));
            double g  = nm * exp(-(ts * ts) * 0.5);
            wf = (float)(ri ? (g * sin(5.0 * ts)) : (g * cos(5.0 * ts)));
        }
        _Float16 hv = (_Float16)wf;
        whi[idx] = hv;
        wlo[idx] = (_Float16)(wf - (float)hv);
    }
}

__global__ __launch_bounds__(BT, 4) void wlsc_main(
    const float* __restrict__ x,
    const float* __restrict__ w1, const float* __restrict__ b1,
    const float* __restrict__ w2, const float* __restrict__ b2,
    const float* __restrict__ blend_logit,
    const float* __restrict__ lsc,
    const _Float16* __restrict__ wfh,
    const _Float16* __restrict__ wfl,
    float* __restrict__ out)
{
    __shared__ float cwtb[NS * RS];                     // 16640 B
    __shared__ __align__(16) char ubuf[NS * H1S * 4];   // 16384 B: xc (stage1) / h1b (2+)
    __shared__ float corr[NS];
    _Float16* xch = (_Float16*)ubuf;          // [NCPY][XCS] hi copies (6336 B)
    _Float16* xcl = xch + NCPY * XCS;         // [NCPY][XCS] lo copies (6336 B)
    float*    h1b = (float*)ubuf;             // overlay for stages 2/3

    const int tid  = threadIdx.x;
    const int tile = blockIdx.x;
    const int bc   = blockIdx.y;
    const int t0   = tile * TW;
    const int c    = bc & (CH - 1);
    const float* xbc = x + (size_t)bc * T_LEN;

    if (tid < NS) corr[tid] = expf(lsc[tid]);

    // ---- stage x window as split-f16 into 4 shifted copies:
    // xc[cp][u] = x[t0-258+u+cp]; one global load per element v, guarded stores ----
    for (int v = tid; v < XWELEM + NCPY; v += BT) {
        int g = t0 - 258 + v;
        if (g < 0)      g = -g;
        if (g >= T_LEN) g = 2 * T_LEN - 2 - g;
        float xv = xbc[g];
        _Float16 hv = (_Float16)xv;
        _Float16 lv = (_Float16)(xv - (float)hv);
        #pragma unroll
        for (int cp = 0; cp < NCPY; ++cp) {
            int idx = v - cp;
            if ((unsigned)idx < XWELEM) {
                xch[cp * XCS + idx] = hv;
                xcl[cp * XCS + idx] = lv;
            }
        }
    }
    __syncthreads();

    // ---- stage 1: CWT via mfma_f32_32x32x16_f16, split-f16 3-product scheme:
    // D = Ah*Bh + Ah*Bl + Al*Bh.  Hankel reuse: frag(mt0+1, kc) = frag(mt0, kc+2),
    // so a 3-deep rotating register queue loads each fragment ONCE — halves
    // the stage-1 LDS A-traffic vs independent per-tile loads. ----
    const int lane = tid & 63;
    const int wid  = tid >> 6;
    const int m    = lane & 31;
    const int h    = lane >> 5;
    const int mt0  = 2 * wid;
    f32x16 acc0, acc1;
    #pragma unroll
    for (int i = 0; i < 16; ++i) { acc0[i] = 0.f; acc1[i] = 0.f; }

    const int abase = (m & 3) * XCS + ((m & ~3) + 8 * h) + mt0 * 32;
    const _Float16* pah = xch + abase;
    const _Float16* pal = xcl + abase;
    const f16x8* wh = reinterpret_cast<const f16x8*>(wfh);
    const f16x8* wl = reinterpret_cast<const f16x8*>(wfl);

    // F(j) = A-frag for x range starting at mt0*32 + 16j (two b64, 8B-aligned)
#define LOADF(p, j) ({                                                        \
        f16x4 _a = *(const f16x4*)((p) + (j) * 16);                           \
        f16x4 _b = *(const f16x4*)((p) + (j) * 16 + 4);                       \
        __builtin_shufflevector(_a, _b, 0,1,2,3,4,5,6,7); })

    f16x8 Fh0 = LOADF(pah, 0), Fl0 = LOADF(pal, 0);
    f16x8 Fh1 = LOADF(pah, 1), Fl1 = LOADF(pal, 1);
    #pragma unroll 3
    for (int kc = 0; kc < NKC; ++kc) {
        f16x8 Fh2 = LOADF(pah, kc + 2);        // fresh: serves mt1 now, mt0 at kc+2
        f16x8 Fl2 = LOADF(pal, kc + 2);
        f16x8 bh = wh[kc * 64 + lane];         // global, L1/L2-hit
        f16x8 bl = wl[kc * 64 + lane];
        // mt0 products use queue head (loaded 2 iterations ago — no load stall)
        acc0 = __builtin_amdgcn_mfma_f32_32x32x16_f16(Fh0, bh, acc0, 0, 0, 0);
        acc0 = __builtin_amdgcn_mfma_f32_32x32x16_f16(Fh0, bl, acc0, 0, 0, 0);
        acc0 = __builtin_amdgcn_mfma_f32_32x32x16_f16(Fl0, bh, acc0, 0, 0, 0);
        // mt1 = mt0+1 products use the fresh fragment (= frag(mt0, kc+2))
        acc1 = __builtin_amdgcn_mfma_f32_32x32x16_f16(Fh2, bh, acc1, 0, 0, 0);
        acc1 = __builtin_amdgcn_mfma_f32_32x32x16_f16(Fh2, bl, acc1, 0, 0, 0);
        acc1 = __builtin_amdgcn_mfma_f32_32x32x16_f16(Fl2, bh, acc1, 0, 0, 0);
        Fh0 = Fh1; Fl0 = Fl1;
        Fh1 = Fh2; Fl1 = Fl2;
    }
#undef LOADF

    // magnitudes: pair (r,i) across lanes n, n^1; even-n lanes store to cwtb.
    // C/D layout: col=lane&31, row=(reg&3)+8*(reg>>2)+4*(lane>>5)  [m74/m101]
    const int s_mine = (lane & 31) >> 1;
    #pragma unroll
    for (int half = 0; half < 2; ++half) {
        f32x16& acc = half ? acc1 : acc0;
        const int mt = mt0 + half;
        #pragma unroll
        for (int g = 0; g < 4; ++g) {
            float4 mag;
            #pragma unroll
            for (int e = 0; e < 4; ++e) {
                float cr = acc[4 * g + e];
                float ci = __shfl_xor(cr, 1);
                float mg = sqrtf(cr * cr + ci * ci);
                int tt = mt * 32 + 8 * g + 4 * h + e;
                int ta = t0 - 2 + tt;                 // zero outside [0,T)
                if ((unsigned)ta >= T_LEN) mg = 0.f;
                (&mag.x)[e] = mg;
            }
            if ((lane & 1) == 0)
                *reinterpret_cast<float4*>(cwtb + s_mine * RS + mt * 32 + 8 * g + 4 * h) = mag;
        }
    }
    __syncthreads();

    // per-channel weights -> registers
    float W1r[9], W2r[9];
    #pragma unroll
    for (int k = 0; k < 9; ++k) { W1r[k] = w1[c * 9 + k]; W2r[k] = w2[c * 9 + k]; }
    const float B1v = b1[c], B2v = b2[c];
    const float blend = 1.f / (1.f + expf(-blend_logit[0]));

    // ---- stage 2: h1 = GELU(dwconv1(cwt*corr)). Thread owns column tt1;
    // unrolled s-loop with sliding 3-value row registers (3 LDS reads/s). ----
    if (tid < TW + 2) {
        const int tt1 = tid;
        const int ta  = t0 - 1 + tt1;
        const bool inb = (unsigned)ta < T_LEN;
        float p0 = 0.f, p1 = 0.f, p2 = 0.f;     // row s-1 (pre-scaled by corr)
        float c0, c1, c2;                        // row s
        {
            float cr = corr[0];
            const float* r = cwtb + tt1;
            c0 = r[0] * cr; c1 = r[1] * cr; c2 = r[2] * cr;
        }
        #pragma unroll
        for (int s = 0; s < NS; ++s) {
            float n0 = 0.f, n1 = 0.f, n2 = 0.f;  // row s+1
            if (s + 1 < NS) {
                float cr = corr[s + 1];
                const float* r = cwtb + (s + 1) * RS + tt1;
                n0 = r[0] * cr; n1 = r[1] * cr; n2 = r[2] * cr;
            }
            float acc = B1v;
            acc = fmaf(p0, W1r[0], acc); acc = fmaf(p1, W1r[1], acc); acc = fmaf(p2, W1r[2], acc);
            acc = fmaf(c0, W1r[3], acc); acc = fmaf(c1, W1r[4], acc); acc = fmaf(c2, W1r[5], acc);
            acc = fmaf(n0, W1r[6], acc); acc = fmaf(n1, W1r[7], acc); acc = fmaf(n2, W1r[8], acc);
            h1b[s * H1S + tt1] = inb ? gelu_exact(acc) : 0.f;
            p0 = c0; p1 = c1; p2 = c2;
            c0 = n0; c1 = n1; c2 = n2;
        }
    }
    __syncthreads();

    // ---- stage 3: h2 = GELU(dwconv2(h1)); blend; mean ratio; out = x*mean ----
    if (tid < TW) {
        const int tt2 = tid;
        const int t   = t0 + tt2;
        float racc = 0.f;
        float p0 = 0.f, p1 = 0.f, p2 = 0.f;
        float c0, c1, c2;
        {
            const float* r = h1b + tt2;
            c0 = r[0]; c1 = r[1]; c2 = r[2];
        }
        #pragma unroll
        for (int s = 0; s < NS; ++s) {
            float n0 = 0.f, n1 = 0.f, n2 = 0.f;
            if (s + 1 < NS) {
                const float* r = h1b + (s + 1) * H1S + tt2;
                n0 = r[0]; n1 = r[1]; n2 = r[2];
            }
            float acc = B2v;
            acc = fmaf(p0, W2r[0], acc); acc = fmaf(p1, W2r[1], acc); acc = fmaf(p2, W2r[2], acc);
            acc = fmaf(c0, W2r[3], acc); acc = fmaf(c1, W2r[4], acc); acc = fmaf(c2, W2r[5], acc);
            acc = fmaf(n0, W2r[6], acc); acc = fmaf(n1, W2r[7], acc); acc = fmaf(n2, W2r[8], acc);
            float h2v = gelu_exact(acc);
            float cv  = cwtb[s * RS + tt2 + 2];
            float num = blend * h2v + (1.f - blend) * cv;
            racc += num / (cv + 1e-8f);
            p0 = c0; p1 = c1; p2 = c2;
            c0 = n0; c1 = n1; c2 = n2;
        }
        if (t < T_LEN)
            out[(size_t)bc * T_LEN + t] = xbc[t] * racc * (1.f / 16.f);
    }
}

extern "C" void kernel_launch(void* const* d_in, const int* in_sizes, int n_in,
                              void* d_out, int out_size, void* d_ws, size_t ws_size,
                              hipStream_t stream) {
    const float* x  = (const float*)d_in[0];
    const float* w1 = (const float*)d_in[1];
    const float* b1 = (const float*)d_in[2];
    const float* w2 = (const float*)d_in[3];
    const float* b2 = (const float*)d_in[4];
    const float* bl = (const float*)d_in[5];
    const float* ls = (const float*)d_in[6];
    float* out = (float*)d_out;

    _Float16* whi = (_Float16*)d_ws;          // NFRAG f16
    _Float16* wlo = whi + NFRAG;              // NFRAG f16

    hipLaunchKernelGGL(wavelet_init, dim3(68), dim3(256), 0, stream, whi, wlo);

    dim3 grid(NTILES, BATCH * CH);
    hipLaunchKernelGGL(wlsc_main, grid, dim3(BT), 0, stream,
                       x, w1, b1, w2, b2, bl, ls, whi, wlo, out);
}

// Round 13
// 279.404 us; speedup vs baseline: 6.0815x; 1.0132x over previous
//
#include <hip/hip_runtime.h>
#include <math.h>

// Problem constants
#define NS     16
#define T_LEN  8192
#define BATCH  8
#define CH     32

// Tiling
#define TW     248        // outputs per block (62 per wave + 2-col shfl halo)
#define BT     256
#define NTILES 34         // ceil(8192/248)
#define RS     260        // cwt row stride (dwords; 260%32=4 spreads s-rows over banks)
#define NKC    33         // K chunks of 16: shared tap window k' in [0,528)
#define XWELEM 784        // x window elems per copy
#define XCS    800        // copy stride in f16 (400 dwords ≡ 16 mod 32: exact 2-way banks)
#define NCPY   4          // shifted copies (b64 alignment: frag start ≡ 0 mod 4)
#define NFRAG  (NKC*512)  // wavelet fragment f16 count per stream

typedef _Float16 f16x4 __attribute__((ext_vector_type(4)));
typedef _Float16 f16x8 __attribute__((ext_vector_type(8)));
typedef float    f32x16 __attribute__((ext_vector_type(16)));

// Per-scale constants (validated rounds 1-12)
constexpr int LT[NS]   = {13,17,23,31,41,55,75,103,139,191,259,351,477,513,513,513};
constexpr int PADT[NS] = {6,8,11,15,20,27,37,51,69,95,129,175,238,256,256,256};

__device__ __forceinline__ float gelu_exact(float v) {
    return 0.5f * v * (1.0f + erff(v * 0.70710678118654752440f));
}

// Regenerate wavelet B-fragment streams (hi + lo split-f16) every launch.
// Element (kc, lane, j) at [kc*512 + lane*8 + j] holds B[k=8*(lane>>5)+j][n=lane&31]
// for chunk kc: tap of scale s=n>>1 (n even=real, odd=imag) at
// j_tap = (kc*16 + k) - 256 + pad_s.  w_f32 = hi + lo with hi=(f16)w_f32.
__global__ void wavelet_init(_Float16* __restrict__ whi, _Float16* __restrict__ wlo) {
    int idx0   = blockIdx.x * blockDim.x + threadIdx.x;
    int stride = gridDim.x * blockDim.x;
    for (int idx = idx0; idx < NFRAG; idx += stride) {
        int kc   = idx >> 9;
        int r    = idx & 511;
        int lane = r >> 3;
        int j    = r & 7;
        int n    = lane & 31;
        int h    = lane >> 5;
        int kp   = kc * 16 + 8 * h + j;      // k' in [0,528+15]
        int s    = n >> 1;
        int ri   = n & 1;
        int L    = LT[s];
        int jt   = kp - 256 + PADT[s];
        float wf = 0.f;
        if (jt >= 0 && jt < L) {
            double e  = (s == NS - 1) ? log10(200.0)
                                      : (log10(2.0) + (double)s * ((log10(200.0) - log10(2.0)) / 15.0));
            double sc = pow(10.0, e);
            double lo = -(double)((L + 1) / 2);   // Python (-L)//2, L odd
            double hi =  (double)(L / 2);
            double st = (hi - lo) / (double)(L - 1);
            double t  = (jt == L - 1) ? hi : (lo + (double)jt * st);
            double ts = t / sc;
            double nm = 1.0 / (pow(M_PI, 0.25) * sqrt(sc));
            double g  = nm * exp(-(ts * ts) * 0.5);
            wf = (float)(ri ? (g * sin(5.0 * ts)) : (g * cos(5.0 * ts)));
        }
        _Float16 hv = (_Float16)wf;
        whi[idx] = hv;
        wlo[idx] = (_Float16)(wf - (float)hv);
    }
}

__global__ __launch_bounds__(BT, 5) void wlsc_main(
    const float* __restrict__ x,
    const float* __restrict__ w1, const float* __restrict__ b1,
    const float* __restrict__ w2, const float* __restrict__ b2,
    const float* __restrict__ blend_logit,
    const float* __restrict__ lsc,
    const _Float16* __restrict__ wfh,
    const _Float16* __restrict__ wfl,
    float* __restrict__ out)
{
    __shared__ float cwtb[NS * RS];                       // 16640 B
    __shared__ __align__(16) char ubuf[2 * NCPY * XCS * 2];  // 12800 B: split-f16 x copies
    __shared__ float corr[NS];
    _Float16* xch = (_Float16*)ubuf;          // [NCPY][XCS] hi copies
    _Float16* xcl = xch + NCPY * XCS;         // [NCPY][XCS] lo copies
    // total LDS = 16640 + 12800 + 64 = 29504 B -> 5 blocks/CU

    const int tid  = threadIdx.x;
    const int tile = blockIdx.x;
    const int bc   = blockIdx.y;
    const int t0   = tile * TW;
    const int c    = bc & (CH - 1);
    const float* xbc = x + (size_t)bc * T_LEN;

    if (tid < NS) corr[tid] = expf(lsc[tid]);

    // ---- stage x window as split-f16 into 4 shifted copies:
    // xc[cp][u] = x[t0-258+u+cp]; one global load per element v, guarded stores ----
    for (int v = tid; v < XWELEM + NCPY; v += BT) {
        int g = t0 - 258 + v;
        if (g < 0)      g = -g;
        if (g >= T_LEN) g = 2 * T_LEN - 2 - g;
        float xv = xbc[g];
        _Float16 hv = (_Float16)xv;
        _Float16 lv = (_Float16)(xv - (float)hv);
        #pragma unroll
        for (int cp = 0; cp < NCPY; ++cp) {
            int idx = v - cp;
            if ((unsigned)idx < XWELEM) {
                xch[cp * XCS + idx] = hv;
                xcl[cp * XCS + idx] = lv;
            }
        }
    }
    __syncthreads();

    // ---- stage 1: CWT via mfma_f32_32x32x16_f16, split-f16 3-product scheme:
    // D = Ah*Bh + Ah*Bl + Al*Bh.  Hankel reuse: frag(mt0+1, kc) = frag(mt0, kc+2),
    // 3-deep rotating register queue loads each fragment once. ----
    const int lane = tid & 63;
    const int wid  = tid >> 6;
    const int m    = lane & 31;
    const int h    = lane >> 5;
    const int mt0  = 2 * wid;
    f32x16 acc0, acc1;
    #pragma unroll
    for (int i = 0; i < 16; ++i) { acc0[i] = 0.f; acc1[i] = 0.f; }

    const int abase = (m & 3) * XCS + ((m & ~3) + 8 * h) + mt0 * 32;
    const _Float16* pah = xch + abase;
    const _Float16* pal = xcl + abase;
    const f16x8* wh = reinterpret_cast<const f16x8*>(wfh);
    const f16x8* wl = reinterpret_cast<const f16x8*>(wfl);

    // F(j) = A-frag for x range starting at mt0*32 + 16j (two b64, 8B-aligned)
#define LOADF(p, j) ({                                                        \
        f16x4 _a = *(const f16x4*)((p) + (j) * 16);                           \
        f16x4 _b = *(const f16x4*)((p) + (j) * 16 + 4);                       \
        __builtin_shufflevector(_a, _b, 0,1,2,3,4,5,6,7); })

    f16x8 Fh0 = LOADF(pah, 0), Fl0 = LOADF(pal, 0);
    f16x8 Fh1 = LOADF(pah, 1), Fl1 = LOADF(pal, 1);
    #pragma unroll 3
    for (int kc = 0; kc < NKC; ++kc) {
        f16x8 Fh2 = LOADF(pah, kc + 2);        // fresh: serves mt1 now, mt0 at kc+2
        f16x8 Fl2 = LOADF(pal, kc + 2);
        f16x8 bh = wh[kc * 64 + lane];         // global, L1/L2-hit
        f16x8 bl = wl[kc * 64 + lane];
        // mt0 products use queue head (loaded 2 iterations ago — no load stall)
        acc0 = __builtin_amdgcn_mfma_f32_32x32x16_f16(Fh0, bh, acc0, 0, 0, 0);
        acc0 = __builtin_amdgcn_mfma_f32_32x32x16_f16(Fh0, bl, acc0, 0, 0, 0);
        acc0 = __builtin_amdgcn_mfma_f32_32x32x16_f16(Fl0, bh, acc0, 0, 0, 0);
        // mt1 = mt0+1 products use the fresh fragment (= frag(mt0, kc+2))
        acc1 = __builtin_amdgcn_mfma_f32_32x32x16_f16(Fh2, bh, acc1, 0, 0, 0);
        acc1 = __builtin_amdgcn_mfma_f32_32x32x16_f16(Fh2, bl, acc1, 0, 0, 0);
        acc1 = __builtin_amdgcn_mfma_f32_32x32x16_f16(Fl2, bh, acc1, 0, 0, 0);
        Fh0 = Fh1; Fl0 = Fl1;
        Fh1 = Fh2; Fl1 = Fl2;
    }
#undef LOADF

    // magnitudes: pair (r,i) across lanes n, n^1; even-n lanes store to cwtb.
    // C/D layout: col=lane&31, row=(reg&3)+8*(reg>>2)+4*(lane>>5)  [m74/m101]
    const int s_mine = (lane & 31) >> 1;
    #pragma unroll
    for (int half = 0; half < 2; ++half) {
        f32x16& acc = half ? acc1 : acc0;
        const int mt = mt0 + half;
        #pragma unroll
        for (int g = 0; g < 4; ++g) {
            float4 mag;
            #pragma unroll
            for (int e = 0; e < 4; ++e) {
                float cr = acc[4 * g + e];
                float ci = __shfl_xor(cr, 1);
                float mg = sqrtf(cr * cr + ci * ci);
                int tt = mt * 32 + 8 * g + 4 * h + e;
                int ta = t0 - 2 + tt;                 // zero outside [0,T)
                if ((unsigned)ta >= T_LEN) mg = 0.f;
                (&mag.x)[e] = mg;
            }
            if ((lane & 1) == 0)
                *reinterpret_cast<float4*>(cwtb + s_mine * RS + mt * 32 + 8 * g + 4 * h) = mag;
        }
    }
    __syncthreads();

    // per-channel weights -> registers
    float W1r[9], W2r[9];
    #pragma unroll
    for (int k = 0; k < 9; ++k) { W1r[k] = w1[c * 9 + k]; W2r[k] = w2[c * 9 + k]; }
    const float B1v = b1[c], B2v = b2[c];
    const float blend = 1.f / (1.f + expf(-blend_logit[0]));

    // ---- stages 2+3 fused: h1 kept in registers, neighbor columns via shfl.
    // Wave wid owns h1 columns tt1 = 62*wid + lane (0..249; lanes 62,63 are
    // halo providers), outputs tt2 = 62*wid + lane for lane < 62. ----
    {
        const int tt1 = 62 * wid + lane;
        const int ta  = t0 - 1 + tt1;
        const bool inb = (unsigned)ta < T_LEN;
        float h1r[NS];     // h1[s] for this column
        float rawcv[NS];   // raw cwt[s][tt1+2] (= cv for stage 3)

        // stage 2: sliding rows, 3 b32 LDS reads per row
        {
            float p0 = 0.f, p1 = 0.f, p2 = 0.f;
            float c0, c1, c2;
            {
                const float* r = cwtb + tt1;
                float cr = corr[0];
                float r2 = r[2];
                rawcv[0] = r2;
                c0 = r[0] * cr; c1 = r[1] * cr; c2 = r2 * cr;
            }
            #pragma unroll
            for (int s = 0; s < NS; ++s) {
                float n0 = 0.f, n1 = 0.f, n2 = 0.f;
                if (s + 1 < NS) {
                    const float* r = cwtb + (s + 1) * RS + tt1;
                    float cr = corr[s + 1];
                    float r2 = r[2];
                    rawcv[s + 1] = r2;
                    n0 = r[0] * cr; n1 = r[1] * cr; n2 = r2 * cr;
                }
                float acc = B1v;
                acc = fmaf(p0, W1r[0], acc); acc = fmaf(p1, W1r[1], acc); acc = fmaf(p2, W1r[2], acc);
                acc = fmaf(c0, W1r[3], acc); acc = fmaf(c1, W1r[4], acc); acc = fmaf(c2, W1r[5], acc);
                acc = fmaf(n0, W1r[6], acc); acc = fmaf(n1, W1r[7], acc); acc = fmaf(n2, W1r[8], acc);
                h1r[s] = inb ? gelu_exact(acc) : 0.f;
                p0 = c0; p1 = c1; p2 = c2;
                c0 = n0; c1 = n1; c2 = n2;
            }
        }

        // stage 3: columns tt2+{0,1,2} = lanes lane, lane+1, lane+2 via shfl_down
        const int tt2 = tt1;
        const int t   = t0 + tt2;
        float racc = 0.f;
        float pa = 0.f, pb = 0.f, pc = 0.f;
        float ca, cb, cc;
        {
            ca = h1r[0];
            cb = __shfl_down(ca, 1);
            cc = __shfl_down(ca, 2);
        }
        #pragma unroll
        for (int s = 0; s < NS; ++s) {
            float na = 0.f, nb = 0.f, nc = 0.f;
            if (s + 1 < NS) {
                na = h1r[s + 1];
                nb = __shfl_down(na, 1);
                nc = __shfl_down(na, 2);
            }
            float acc = B2v;
            acc = fmaf(pa, W2r[0], acc); acc = fmaf(pb, W2r[1], acc); acc = fmaf(pc, W2r[2], acc);
            acc = fmaf(ca, W2r[3], acc); acc = fmaf(cb, W2r[4], acc); acc = fmaf(cc, W2r[5], acc);
            acc = fmaf(na, W2r[6], acc); acc = fmaf(nb, W2r[7], acc); acc = fmaf(nc, W2r[8], acc);
            float h2v = gelu_exact(acc);
            float cv  = rawcv[s];
            float num = blend * h2v + (1.f - blend) * cv;
            racc += num / (cv + 1e-8f);
            pa = ca; pb = cb; pc = cc;
            ca = na; cb = nb; cc = nc;
        }
        if (lane < 62 && t < T_LEN)
            out[(size_t)bc * T_LEN + t] = xbc[t] * racc * (1.f / 16.f);
    }
}

extern "C" void kernel_launch(void* const* d_in, const int* in_sizes, int n_in,
                              void* d_out, int out_size, void* d_ws, size_t ws_size,
                              hipStream_t stream) {
    const float* x  = (const float*)d_in[0];
    const float* w1 = (const float*)d_in[1];
    const float* b1 = (const float*)d_in[2];
    const float* w2 = (const float*)d_in[3];
    const float* b2 = (const float*)d_in[4];
    const float* bl = (const float*)d_in[5];
    const float* ls = (const float*)d_in[6];
    float* out = (float*)d_out;

    _Float16* whi = (_Float16*)d_ws;          // NFRAG f16
    _Float16* wlo = whi + NFRAG;              // NFRAG f16

    hipLaunchKernelGGL(wavelet_init, dim3(68), dim3(256), 0, stream, whi, wlo);

    dim3 grid(NTILES, BATCH * CH);
    hipLaunchKernelGGL(wlsc_main, grid, dim3(BT), 0, stream,
                       x, w1, b1, w2, b2, bl, ls, whi, wlo, out);
}